// Round 2
// baseline (119.891 us; speedup 1.0000x reference)
//
#include <hip/hip_runtime.h>

#define NB 1024      // num 4x4 blocks
#define DD 4096      // feature dim = NB * 4
#define EPS 1e-5f

typedef float f4 __attribute__((ext_vector_type(4)));

// One thread per block-index b. Computes Q_b = (I - S) * inv((1+eps)I + S)
// in registers once, then streams rows: out[n,b,:] = Q_b @ x[n,b,:].
// Row loop unrolled x4 with independent non-temporal loads for MLP.
__global__ __launch_bounds__(256) void oft_apply_kernel(
    const f4* __restrict__ x4,
    const float* __restrict__ oft_r,
    f4* __restrict__ out4,
    int nrows)
{
    const int b = blockIdx.x * 256 + threadIdx.x;   // 0..NB-1 (gridDim.x = NB/256)

    // ---- load R_b (row-major 4x4) ----
    const f4* Rb = reinterpret_cast<const f4*>(oft_r + (size_t)b * 16);
    float R[16];
    #pragma unroll
    for (int k = 0; k < 4; ++k) {
        f4 v = Rb[k];
        R[4*k+0] = v.x; R[4*k+1] = v.y; R[4*k+2] = v.z; R[4*k+3] = v.w;
    }

    // ---- S = R - R^T ;  A = (1+eps)I + S ----
    float m[16];
    #pragma unroll
    for (int i = 0; i < 4; ++i)
        #pragma unroll
        for (int j = 0; j < 4; ++j) {
            float s = R[4*i+j] - R[4*j+i];
            m[4*i+j] = s + ((i == j) ? (1.0f + EPS) : 0.0f);
        }

    // ---- inv(A) via adjugate (A is near-identity, well conditioned) ----
    float inv[16];
    inv[0]  =  m[5]*m[10]*m[15] - m[5]*m[11]*m[14] - m[9]*m[6]*m[15] + m[9]*m[7]*m[14] + m[13]*m[6]*m[11] - m[13]*m[7]*m[10];
    inv[4]  = -m[4]*m[10]*m[15] + m[4]*m[11]*m[14] + m[8]*m[6]*m[15] - m[8]*m[7]*m[14] - m[12]*m[6]*m[11] + m[12]*m[7]*m[10];
    inv[8]  =  m[4]*m[9]*m[15]  - m[4]*m[11]*m[13] - m[8]*m[5]*m[15] + m[8]*m[7]*m[13] + m[12]*m[5]*m[11] - m[12]*m[7]*m[9];
    inv[12] = -m[4]*m[9]*m[14]  + m[4]*m[10]*m[13] + m[8]*m[5]*m[14] - m[8]*m[6]*m[13] - m[12]*m[5]*m[10] + m[12]*m[6]*m[9];
    inv[1]  = -m[1]*m[10]*m[15] + m[1]*m[11]*m[14] + m[9]*m[2]*m[15] - m[9]*m[3]*m[14] - m[13]*m[2]*m[11] + m[13]*m[3]*m[10];
    inv[5]  =  m[0]*m[10]*m[15] - m[0]*m[11]*m[14] - m[8]*m[2]*m[15] + m[8]*m[3]*m[14] + m[12]*m[2]*m[11] - m[12]*m[3]*m[10];
    inv[9]  = -m[0]*m[9]*m[15]  + m[0]*m[11]*m[13] + m[8]*m[1]*m[15] - m[8]*m[3]*m[13] - m[12]*m[1]*m[11] + m[12]*m[3]*m[9];
    inv[13] =  m[0]*m[9]*m[14]  - m[0]*m[10]*m[13] - m[8]*m[1]*m[14] + m[8]*m[2]*m[13] + m[12]*m[1]*m[10] - m[12]*m[2]*m[9];
    inv[2]  =  m[1]*m[6]*m[15]  - m[1]*m[7]*m[14]  - m[5]*m[2]*m[15] + m[5]*m[3]*m[14] + m[13]*m[2]*m[7]  - m[13]*m[3]*m[6];
    inv[6]  = -m[0]*m[6]*m[15]  + m[0]*m[7]*m[14]  + m[4]*m[2]*m[15] - m[4]*m[3]*m[14] - m[12]*m[2]*m[7]  + m[12]*m[3]*m[6];
    inv[10] =  m[0]*m[5]*m[15]  - m[0]*m[7]*m[13]  - m[4]*m[1]*m[15] + m[4]*m[3]*m[13] + m[12]*m[1]*m[7]  - m[12]*m[3]*m[5];
    inv[14] = -m[0]*m[5]*m[14]  + m[0]*m[6]*m[13]  + m[4]*m[1]*m[14] - m[4]*m[2]*m[13] - m[12]*m[1]*m[6]  + m[12]*m[2]*m[5];
    inv[3]  = -m[1]*m[6]*m[11]  + m[1]*m[7]*m[10]  + m[5]*m[2]*m[11] - m[5]*m[3]*m[10] - m[9]*m[2]*m[7]   + m[9]*m[3]*m[6];
    inv[7]  =  m[0]*m[6]*m[11]  - m[0]*m[7]*m[10]  - m[4]*m[2]*m[11] + m[4]*m[3]*m[10] + m[8]*m[2]*m[7]   - m[8]*m[3]*m[6];
    inv[11] = -m[0]*m[5]*m[11]  + m[0]*m[7]*m[9]   + m[4]*m[1]*m[11] - m[4]*m[3]*m[9]  - m[8]*m[1]*m[7]   + m[8]*m[3]*m[5];
    inv[15] =  m[0]*m[5]*m[10]  - m[0]*m[6]*m[9]   - m[4]*m[1]*m[10] + m[4]*m[2]*m[9]  + m[8]*m[1]*m[6]   - m[8]*m[2]*m[5];

    float det = m[0]*inv[0] + m[1]*inv[4] + m[2]*inv[8] + m[3]*inv[12];
    float invdet = 1.0f / det;
    #pragma unroll
    for (int k = 0; k < 16; ++k) inv[k] *= invdet;

    // ---- Q = (I - S) @ inv(A) ----
    float Q[4][4];
    #pragma unroll
    for (int j = 0; j < 4; ++j)
        #pragma unroll
        for (int i = 0; i < 4; ++i) {
            float acc = 0.0f;
            #pragma unroll
            for (int k = 0; k < 4; ++k) {
                float s_jk = R[4*j+k] - R[4*k+j];
                float b_jk = ((j == k) ? 1.0f : 0.0f) - s_jk;
                acc += b_jk * inv[4*k+i];
            }
            Q[j][i] = acc;
        }

    // ---- stream rows: y = Q_b @ x, unrolled x4 for MLP ----
    const int G = gridDim.y;                 // row stride between iterations
    const size_t rowq = DD / 4;              // float4s per row
    int n = blockIdx.y;

    for (; n + 3 * G < nrows; n += 4 * G) {
        size_t i0 = (size_t)n * rowq + b;
        size_t i1 = i0 + (size_t)G * rowq;
        size_t i2 = i1 + (size_t)G * rowq;
        size_t i3 = i2 + (size_t)G * rowq;
        f4 v0 = __builtin_nontemporal_load(x4 + i0);
        f4 v1 = __builtin_nontemporal_load(x4 + i1);
        f4 v2 = __builtin_nontemporal_load(x4 + i2);
        f4 v3 = __builtin_nontemporal_load(x4 + i3);

        f4 y0, y1, y2, y3;
        y0.x = Q[0][0]*v0.x + Q[0][1]*v0.y + Q[0][2]*v0.z + Q[0][3]*v0.w;
        y0.y = Q[1][0]*v0.x + Q[1][1]*v0.y + Q[1][2]*v0.z + Q[1][3]*v0.w;
        y0.z = Q[2][0]*v0.x + Q[2][1]*v0.y + Q[2][2]*v0.z + Q[2][3]*v0.w;
        y0.w = Q[3][0]*v0.x + Q[3][1]*v0.y + Q[3][2]*v0.z + Q[3][3]*v0.w;
        y1.x = Q[0][0]*v1.x + Q[0][1]*v1.y + Q[0][2]*v1.z + Q[0][3]*v1.w;
        y1.y = Q[1][0]*v1.x + Q[1][1]*v1.y + Q[1][2]*v1.z + Q[1][3]*v1.w;
        y1.z = Q[2][0]*v1.x + Q[2][1]*v1.y + Q[2][2]*v1.z + Q[2][3]*v1.w;
        y1.w = Q[3][0]*v1.x + Q[3][1]*v1.y + Q[3][2]*v1.z + Q[3][3]*v1.w;
        y2.x = Q[0][0]*v2.x + Q[0][1]*v2.y + Q[0][2]*v2.z + Q[0][3]*v2.w;
        y2.y = Q[1][0]*v2.x + Q[1][1]*v2.y + Q[1][2]*v2.z + Q[1][3]*v2.w;
        y2.z = Q[2][0]*v2.x + Q[2][1]*v2.y + Q[2][2]*v2.z + Q[2][3]*v2.w;
        y2.w = Q[3][0]*v2.x + Q[3][1]*v2.y + Q[3][2]*v2.z + Q[3][3]*v2.w;
        y3.x = Q[0][0]*v3.x + Q[0][1]*v3.y + Q[0][2]*v3.z + Q[0][3]*v3.w;
        y3.y = Q[1][0]*v3.x + Q[1][1]*v3.y + Q[1][2]*v3.z + Q[1][3]*v3.w;
        y3.z = Q[2][0]*v3.x + Q[2][1]*v3.y + Q[2][2]*v3.z + Q[2][3]*v3.w;
        y3.w = Q[3][0]*v3.x + Q[3][1]*v3.y + Q[3][2]*v3.z + Q[3][3]*v3.w;

        __builtin_nontemporal_store(y0, out4 + i0);
        __builtin_nontemporal_store(y1, out4 + i1);
        __builtin_nontemporal_store(y2, out4 + i2);
        __builtin_nontemporal_store(y3, out4 + i3);
    }
    // tail (not taken for 16384 rows / G=512, kept for safety)
    for (; n < nrows; n += G) {
        size_t i0 = (size_t)n * rowq + b;
        f4 v = __builtin_nontemporal_load(x4 + i0);
        f4 y;
        y.x = Q[0][0]*v.x + Q[0][1]*v.y + Q[0][2]*v.z + Q[0][3]*v.w;
        y.y = Q[1][0]*v.x + Q[1][1]*v.y + Q[1][2]*v.z + Q[1][3]*v.w;
        y.z = Q[2][0]*v.x + Q[2][1]*v.y + Q[2][2]*v.z + Q[2][3]*v.w;
        y.w = Q[3][0]*v.x + Q[3][1]*v.y + Q[3][2]*v.z + Q[3][3]*v.w;
        __builtin_nontemporal_store(y, out4 + i0);
    }
}

extern "C" void kernel_launch(void* const* d_in, const int* in_sizes, int n_in,
                              void* d_out, int out_size, void* d_ws, size_t ws_size,
                              hipStream_t stream) {
    const float* x     = (const float*)d_in[0];   // [4,4096,4096] fp32
    const float* oft_r = (const float*)d_in[1];   // [1024,4,4] fp32
    float* out = (float*)d_out;

    const int nrows = in_sizes[0] / DD;           // 16384

    dim3 block(256, 1, 1);
    dim3 grid(NB / 256, 512, 1);                  // 4 x 512 = 2048 WGs, 8/CU
    oft_apply_kernel<<<grid, block, 0, stream>>>(
        reinterpret_cast<const f4*>(x), oft_r,
        reinterpret_cast<f4*>(out), nrows);
}

// Round 4
// 108.517 us; speedup vs baseline: 1.1048x; 1.1048x over previous
//
#include <hip/hip_runtime.h>

#define NB 1024      // num 4x4 blocks
#define DD 4096      // feature dim = NB * 4
#define EPS 1e-5f

typedef float f4 __attribute__((ext_vector_type(4)));

struct Mat4 { float q[4][4]; };

static __device__ __forceinline__ f4 matvec(const Mat4& M, f4 v) {
    f4 r;
    r.x = M.q[0][0]*v.x + M.q[0][1]*v.y + M.q[0][2]*v.z + M.q[0][3]*v.w;
    r.y = M.q[1][0]*v.x + M.q[1][1]*v.y + M.q[1][2]*v.z + M.q[1][3]*v.w;
    r.z = M.q[2][0]*v.x + M.q[2][1]*v.y + M.q[2][2]*v.z + M.q[2][3]*v.w;
    r.w = M.q[3][0]*v.x + M.q[3][1]*v.y + M.q[3][2]*v.z + M.q[3][3]*v.w;
    return r;
}

// One thread per block-index b. Computes Q_b = (I - S) * inv((1+eps)I + S)
// in registers once, then streams rows in ADJACENT pairs (2p, 2p+1) with
// explicit software pipelining: next pair's loads are issued before the
// current pair's compute+store, so the compute's s_waitcnt resolves without
// draining outstanding stores (vmcnt is in-order and shared by loads+stores
// on gfx9-lineage).
__global__ __launch_bounds__(256) void oft_apply_kernel(
    const f4* __restrict__ x4,
    const float* __restrict__ oft_r,
    f4* __restrict__ out4,
    int nrows)
{
    const int b = blockIdx.x * 256 + threadIdx.x;   // 0..NB-1 (gridDim.x = NB/256)

    // ---- load R_b (row-major 4x4) ----
    const f4* Rb = reinterpret_cast<const f4*>(oft_r + (size_t)b * 16);
    float R[16];
    #pragma unroll
    for (int k = 0; k < 4; ++k) {
        f4 v = Rb[k];
        R[4*k+0] = v.x; R[4*k+1] = v.y; R[4*k+2] = v.z; R[4*k+3] = v.w;
    }

    // ---- S = R - R^T ;  A = (1+eps)I + S ----
    float m[16];
    #pragma unroll
    for (int i = 0; i < 4; ++i)
        #pragma unroll
        for (int j = 0; j < 4; ++j) {
            float s = R[4*i+j] - R[4*j+i];
            m[4*i+j] = s + ((i == j) ? (1.0f + EPS) : 0.0f);
        }

    // ---- inv(A) via adjugate (A is near-identity, well conditioned) ----
    float inv[16];
    inv[0]  =  m[5]*m[10]*m[15] - m[5]*m[11]*m[14] - m[9]*m[6]*m[15] + m[9]*m[7]*m[14] + m[13]*m[6]*m[11] - m[13]*m[7]*m[10];
    inv[4]  = -m[4]*m[10]*m[15] + m[4]*m[11]*m[14] + m[8]*m[6]*m[15] - m[8]*m[7]*m[14] - m[12]*m[6]*m[11] + m[12]*m[7]*m[10];
    inv[8]  =  m[4]*m[9]*m[15]  - m[4]*m[11]*m[13] - m[8]*m[5]*m[15] + m[8]*m[7]*m[13] + m[12]*m[5]*m[11] - m[12]*m[7]*m[9];
    inv[12] = -m[4]*m[9]*m[14]  + m[4]*m[10]*m[13] + m[8]*m[5]*m[14] - m[8]*m[6]*m[13] - m[12]*m[5]*m[10] + m[12]*m[6]*m[9];
    inv[1]  = -m[1]*m[10]*m[15] + m[1]*m[11]*m[14] + m[9]*m[2]*m[15] - m[9]*m[3]*m[14] - m[13]*m[2]*m[11] + m[13]*m[3]*m[10];
    inv[5]  =  m[0]*m[10]*m[15] - m[0]*m[11]*m[14] - m[8]*m[2]*m[15] + m[8]*m[3]*m[14] + m[12]*m[2]*m[11] - m[12]*m[3]*m[10];
    inv[9]  = -m[0]*m[9]*m[15]  + m[0]*m[11]*m[13] + m[8]*m[1]*m[15] - m[8]*m[3]*m[13] - m[12]*m[1]*m[11] + m[12]*m[3]*m[9];
    inv[13] =  m[0]*m[9]*m[14]  - m[0]*m[10]*m[13] - m[8]*m[1]*m[14] + m[8]*m[2]*m[13] + m[12]*m[1]*m[10] - m[12]*m[2]*m[9];
    inv[2]  =  m[1]*m[6]*m[15]  - m[1]*m[7]*m[14]  - m[5]*m[2]*m[15] + m[5]*m[3]*m[14] + m[13]*m[2]*m[7]  - m[13]*m[3]*m[6];
    inv[6]  = -m[0]*m[6]*m[15]  + m[0]*m[7]*m[14]  + m[4]*m[2]*m[15] - m[4]*m[3]*m[14] - m[12]*m[2]*m[7]  + m[12]*m[3]*m[6];
    inv[10] =  m[0]*m[5]*m[15]  - m[0]*m[7]*m[13]  - m[4]*m[1]*m[15] + m[4]*m[3]*m[13] + m[12]*m[1]*m[7]  - m[12]*m[3]*m[5];
    inv[14] = -m[0]*m[5]*m[14]  + m[0]*m[6]*m[13]  + m[4]*m[1]*m[14] - m[4]*m[2]*m[13] - m[12]*m[1]*m[6]  + m[12]*m[2]*m[5];
    inv[3]  = -m[1]*m[6]*m[11]  + m[1]*m[7]*m[10]  + m[5]*m[2]*m[11] - m[5]*m[3]*m[10] - m[9]*m[2]*m[7]   + m[9]*m[3]*m[6];
    inv[7]  =  m[0]*m[6]*m[11]  - m[0]*m[7]*m[10]  - m[4]*m[2]*m[11] + m[4]*m[3]*m[10] + m[8]*m[2]*m[7]   - m[8]*m[3]*m[6];
    inv[11] = -m[0]*m[5]*m[11]  + m[0]*m[7]*m[9]   + m[4]*m[1]*m[11] - m[4]*m[3]*m[9]  - m[8]*m[1]*m[7]   + m[8]*m[3]*m[5];
    inv[15] =  m[0]*m[5]*m[10]  - m[0]*m[6]*m[9]   - m[4]*m[1]*m[10] + m[4]*m[2]*m[9]  + m[8]*m[1]*m[6]   - m[8]*m[2]*m[5];

    float det = m[0]*inv[0] + m[1]*inv[4] + m[2]*inv[8] + m[3]*inv[12];
    float invdet = 1.0f / det;
    #pragma unroll
    for (int k = 0; k < 16; ++k) inv[k] *= invdet;

    // ---- Q = (I - S) @ inv(A) ----
    Mat4 M;
    #pragma unroll
    for (int j = 0; j < 4; ++j)
        #pragma unroll
        for (int i = 0; i < 4; ++i) {
            float acc = 0.0f;
            #pragma unroll
            for (int k = 0; k < 4; ++k) {
                float s_jk = R[4*j+k] - R[4*k+j];
                float b_jk = ((j == k) ? 1.0f : 0.0f) - s_jk;
                acc += b_jk * inv[4*k+i];
            }
            M.q[j][i] = acc;
        }

    const int G = gridDim.y;              // pair stride
    const size_t rowq = DD / 4;           // float4s per row
    const int npairs = nrows >> 1;

    int p = blockIdx.y;
    if (p < npairs) {
        // prologue: load first pair (adjacent rows 2p, 2p+1)
        size_t i0 = (size_t)(2 * p) * rowq + b;
        f4 va = x4[i0];
        f4 vb = x4[i0 + rowq];

        for (;;) {
            const int pn = p + G;
            const bool has_next = pn < npairs;
            size_t j0 = 0;
            f4 vc, vd;
            if (has_next) {
                // issue next pair's loads BEFORE compute/store of current
                j0 = (size_t)(2 * pn) * rowq + b;
                vc = x4[j0];
                vd = x4[j0 + rowq];
            }

            f4 ya = matvec(M, va);
            f4 yb = matvec(M, vb);
            out4[i0] = ya;
            out4[i0 + rowq] = yb;

            if (!has_next) break;
            va = vc; vb = vd; i0 = j0; p = pn;
        }
    }

    // odd-row tail (not taken for nrows=16384; kept for generality)
    if (nrows & 1) {
        if (blockIdx.y == 0) {
            size_t i0 = (size_t)(nrows - 1) * rowq + b;
            f4 v = x4[i0];
            f4 yv = matvec(M, v);
            out4[i0] = yv;
        }
    }
}

extern "C" void kernel_launch(void* const* d_in, const int* in_sizes, int n_in,
                              void* d_out, int out_size, void* d_ws, size_t ws_size,
                              hipStream_t stream) {
    const float* x     = (const float*)d_in[0];   // [4,4096,4096] fp32
    const float* oft_r = (const float*)d_in[1];   // [1024,4,4] fp32
    float* out = (float*)d_out;

    const int nrows = in_sizes[0] / DD;           // 16384

    dim3 block(256, 1, 1);
    dim3 grid(NB / 256, 512, 1);                  // 4 x 512 = 2048 WGs, 8/CU
    oft_apply_kernel<<<grid, block, 0, stream>>>(
        reinterpret_cast<const f4*>(x), oft_r,
        reinterpret_cast<f4*>(out), nrows);
}

// Round 5
// 85.813 us; speedup vs baseline: 1.3971x; 1.2646x over previous
//
#include <hip/hip_runtime.h>

#define NB 1024      // num 4x4 blocks
#define DD 4096      // feature dim = NB * 4
#define EPS 1e-5f

typedef float f4 __attribute__((ext_vector_type(4)));

struct Mat4 { float q[4][4]; };

static __device__ __forceinline__ f4 matvec(const Mat4& M, f4 v) {
    f4 r;
    r.x = M.q[0][0]*v.x + M.q[0][1]*v.y + M.q[0][2]*v.z + M.q[0][3]*v.w;
    r.y = M.q[1][0]*v.x + M.q[1][1]*v.y + M.q[1][2]*v.z + M.q[1][3]*v.w;
    r.z = M.q[2][0]*v.x + M.q[2][1]*v.y + M.q[2][2]*v.z + M.q[2][3]*v.w;
    r.w = M.q[3][0]*v.x + M.q[3][1]*v.y + M.q[3][2]*v.z + M.q[3][3]*v.w;
    return r;
}

// One thread per block-index b. Q_b computed once in registers, then streams
// rows in adjacent pairs (2p, 2p+1), software-pipelined (next pair's loads
// issued before current pair's compute+store). R5 A/B: output stores are
// NON-TEMPORAL (streaming hint — skip L2 allocate/dirty churn); loads plain.
__global__ __launch_bounds__(256) void oft_apply_kernel(
    const f4* __restrict__ x4,
    const float* __restrict__ oft_r,
    f4* __restrict__ out4,
    int nrows)
{
    const int b = blockIdx.x * 256 + threadIdx.x;   // 0..NB-1 (gridDim.x = NB/256)

    // ---- load R_b (row-major 4x4) ----
    const f4* Rb = reinterpret_cast<const f4*>(oft_r + (size_t)b * 16);
    float R[16];
    #pragma unroll
    for (int k = 0; k < 4; ++k) {
        f4 v = Rb[k];
        R[4*k+0] = v.x; R[4*k+1] = v.y; R[4*k+2] = v.z; R[4*k+3] = v.w;
    }

    // ---- S = R - R^T ;  A = (1+eps)I + S ----
    float m[16];
    #pragma unroll
    for (int i = 0; i < 4; ++i)
        #pragma unroll
        for (int j = 0; j < 4; ++j) {
            float s = R[4*i+j] - R[4*j+i];
            m[4*i+j] = s + ((i == j) ? (1.0f + EPS) : 0.0f);
        }

    // ---- inv(A) via adjugate (A is near-identity, well conditioned) ----
    float inv[16];
    inv[0]  =  m[5]*m[10]*m[15] - m[5]*m[11]*m[14] - m[9]*m[6]*m[15] + m[9]*m[7]*m[14] + m[13]*m[6]*m[11] - m[13]*m[7]*m[10];
    inv[4]  = -m[4]*m[10]*m[15] + m[4]*m[11]*m[14] + m[8]*m[6]*m[15] - m[8]*m[7]*m[14] - m[12]*m[6]*m[11] + m[12]*m[7]*m[10];
    inv[8]  =  m[4]*m[9]*m[15]  - m[4]*m[11]*m[13] - m[8]*m[5]*m[15] + m[8]*m[7]*m[13] + m[12]*m[5]*m[11] - m[12]*m[7]*m[9];
    inv[12] = -m[4]*m[9]*m[14]  + m[4]*m[10]*m[13] + m[8]*m[5]*m[14] - m[8]*m[6]*m[13] - m[12]*m[5]*m[10] + m[12]*m[6]*m[9];
    inv[1]  = -m[1]*m[10]*m[15] + m[1]*m[11]*m[14] + m[9]*m[2]*m[15] - m[9]*m[3]*m[14] - m[13]*m[2]*m[11] + m[13]*m[3]*m[10];
    inv[5]  =  m[0]*m[10]*m[15] - m[0]*m[11]*m[14] - m[8]*m[2]*m[15] + m[8]*m[3]*m[14] + m[12]*m[2]*m[11] - m[12]*m[3]*m[10];
    inv[9]  = -m[0]*m[9]*m[15]  + m[0]*m[11]*m[13] + m[8]*m[1]*m[15] - m[8]*m[3]*m[13] - m[12]*m[1]*m[11] + m[12]*m[3]*m[9];
    inv[13] =  m[0]*m[9]*m[14]  - m[0]*m[10]*m[13] - m[8]*m[1]*m[14] + m[8]*m[2]*m[13] + m[12]*m[1]*m[10] - m[12]*m[2]*m[9];
    inv[2]  =  m[1]*m[6]*m[15]  - m[1]*m[7]*m[14]  - m[5]*m[2]*m[15] + m[5]*m[3]*m[14] + m[13]*m[2]*m[7]  - m[13]*m[3]*m[6];
    inv[6]  = -m[0]*m[6]*m[15]  + m[0]*m[7]*m[14]  + m[4]*m[2]*m[15] - m[4]*m[3]*m[14] - m[12]*m[2]*m[7]  + m[12]*m[3]*m[6];
    inv[10] =  m[0]*m[5]*m[15]  - m[0]*m[7]*m[13]  - m[4]*m[1]*m[15] + m[4]*m[3]*m[13] + m[12]*m[1]*m[7]  - m[12]*m[3]*m[5];
    inv[14] = -m[0]*m[5]*m[14]  + m[0]*m[6]*m[13]  + m[4]*m[1]*m[14] - m[4]*m[2]*m[13] - m[12]*m[1]*m[6]  + m[12]*m[2]*m[5];
    inv[3]  = -m[1]*m[6]*m[11]  + m[1]*m[7]*m[10]  + m[5]*m[2]*m[11] - m[5]*m[3]*m[10] - m[9]*m[2]*m[7]   + m[9]*m[3]*m[6];
    inv[7]  =  m[0]*m[6]*m[11]  - m[0]*m[7]*m[10]  - m[4]*m[2]*m[11] + m[4]*m[3]*m[10] + m[8]*m[2]*m[7]   - m[8]*m[3]*m[6];
    inv[11] = -m[0]*m[5]*m[11]  + m[0]*m[7]*m[9]   + m[4]*m[1]*m[11] - m[4]*m[3]*m[9]  - m[8]*m[1]*m[7]   + m[8]*m[3]*m[5];
    inv[15] =  m[0]*m[5]*m[10]  - m[0]*m[6]*m[9]   - m[4]*m[1]*m[10] + m[4]*m[2]*m[9]  + m[8]*m[1]*m[6]   - m[8]*m[2]*m[5];

    float det = m[0]*inv[0] + m[1]*inv[4] + m[2]*inv[8] + m[3]*inv[12];
    float invdet = 1.0f / det;
    #pragma unroll
    for (int k = 0; k < 16; ++k) inv[k] *= invdet;

    // ---- Q = (I - S) @ inv(A) ----
    Mat4 M;
    #pragma unroll
    for (int j = 0; j < 4; ++j)
        #pragma unroll
        for (int i = 0; i < 4; ++i) {
            float acc = 0.0f;
            #pragma unroll
            for (int k = 0; k < 4; ++k) {
                float s_jk = R[4*j+k] - R[4*k+j];
                float b_jk = ((j == k) ? 1.0f : 0.0f) - s_jk;
                acc += b_jk * inv[4*k+i];
            }
            M.q[j][i] = acc;
        }

    const int G = gridDim.y;              // pair stride
    const size_t rowq = DD / 4;           // float4s per row
    const int npairs = nrows >> 1;

    int p = blockIdx.y;
    if (p < npairs) {
        // prologue: load first pair (adjacent rows 2p, 2p+1)
        size_t i0 = (size_t)(2 * p) * rowq + b;
        f4 va = x4[i0];
        f4 vb = x4[i0 + rowq];

        for (;;) {
            const int pn = p + G;
            const bool has_next = pn < npairs;
            size_t j0 = 0;
            f4 vc, vd;
            if (has_next) {
                // issue next pair's loads BEFORE compute/store of current
                j0 = (size_t)(2 * pn) * rowq + b;
                vc = x4[j0];
                vd = x4[j0 + rowq];
            }

            f4 ya = matvec(M, va);
            f4 yb = matvec(M, vb);
            __builtin_nontemporal_store(ya, out4 + i0);
            __builtin_nontemporal_store(yb, out4 + i0 + rowq);

            if (!has_next) break;
            va = vc; vb = vd; i0 = j0; p = pn;
        }
    }

    // odd-row tail (not taken for nrows=16384; kept for generality)
    if (nrows & 1) {
        if (blockIdx.y == 0) {
            size_t i0 = (size_t)(nrows - 1) * rowq + b;
            f4 v = x4[i0];
            f4 yv = matvec(M, v);
            __builtin_nontemporal_store(yv, out4 + i0);
        }
    }
}

extern "C" void kernel_launch(void* const* d_in, const int* in_sizes, int n_in,
                              void* d_out, int out_size, void* d_ws, size_t ws_size,
                              hipStream_t stream) {
    const float* x     = (const float*)d_in[0];   // [4,4096,4096] fp32
    const float* oft_r = (const float*)d_in[1];   // [1024,4,4] fp32
    float* out = (float*)d_out;

    const int nrows = in_sizes[0] / DD;           // 16384

    dim3 block(256, 1, 1);
    dim3 grid(NB / 256, 512, 1);                  // 4 x 512 = 2048 WGs, 8/CU
    oft_apply_kernel<<<grid, block, 0, stream>>>(
        reinterpret_cast<const f4*>(x), oft_r,
        reinterpret_cast<f4*>(out), nrows);
}